// Round 3
// 1080.435 us; speedup vs baseline: 1.0949x; 1.0949x over previous
//
#include <hip/hip_runtime.h>
#include <cstdint>
#include <cstddef>

// DeltaMPredictor: proj(2048->512) + per-cam LN + per-cam SwiGLU + proj->36
// + skew/clip/expm(6x6).
//
// R3 structure: K1 is a single fused kernel (k_projln) that reads thumbnails
// fp32 ONCE (reg-staged fp32->bf16 conversion with 1-step register prefetch),
// computes full 512-col row panels (128x512 per 512-thread block) so the
// LayerNorm row reduction fuses into the epilogue. Eliminates k_cvt8 (804 MB),
// the regb round-trip (134 MB) and the k_ln launch. ws need: ~141 MB.
// R3 delta vs R2: removed the min-waves/EU launch_bounds hint (risk factor
// for allocator-forced spill; block size alone already implies the cap).

#define B_SZ   16384
#define C_CAM  4
#define DBB    2048
#define D_H    512

typedef __attribute__((ext_vector_type(8))) short  bf16x8;
typedef __attribute__((ext_vector_type(4))) float  f32x4;

__device__ __forceinline__ unsigned short f2b(float f) {
    union { float f; unsigned u; } v; v.f = f;
    unsigned r = (v.u + 0x7FFFu + ((v.u >> 16) & 1u)) >> 16;   // RNE
    return (unsigned short)r;
}
__device__ __forceinline__ float b2f(unsigned short u) {
    union { unsigned u; float f; } v; v.u = ((unsigned)u) << 16;
    return v.f;
}

// async global->LDS, 16B per lane, dest = wave-uniform base + lane*16
#define GLDS(g, l) __builtin_amdgcn_global_load_lds( \
    (const __attribute__((address_space(1))) unsigned int*)(g), \
    (__attribute__((address_space(3))) unsigned int*)(l), 16, 0, 0)

// ---------------- weight conversion ----------------
__global__ void k_cvt(const float* __restrict__ src, unsigned short* __restrict__ dst, int n) {
    int i = blockIdx.x * blockDim.x + threadIdx.x;
    int stride = gridDim.x * blockDim.x;
    for (; i < n; i += stride) dst[i] = f2b(src[i]);
}

// w_out [C,36,512] -> bf16 padded to [C,48,512], rows 36..47 zero
__global__ void k_cvt_wout(const float* __restrict__ src, unsigned short* __restrict__ dst) {
    int i = blockIdx.x * blockDim.x + threadIdx.x;
    if (i >= C_CAM * 48 * D_H) return;
    int col = i & (D_H - 1);
    int row = (i >> 9) % 48;
    int c   = i / (48 * D_H);
    dst[i] = (row < 36) ? f2b(src[((size_t)c * 36 + row) * D_H + col]) : (unsigned short)0;
}

// ---------------- K1 fused: proj GEMM (fp32 A, read once) + bias + LayerNorm ----------------
// Block = 512 threads (8 waves, 2x4), computes rows [tile_m, tile_m+128) x all 512 cols.
// A staged via regs (fp32 load + cvt + ds_write), prefetched one K-step ahead;
// B (proj_w bf16 [512][2048]) staged via global_load_lds width=16.
// LDS tiles [*][32] unpadded (k_projb's proven bank-balanced layout).
// Epilogue: bias -> LN stats (shfl over 16 lr-lanes + 4-wave LDS reduce) -> gamma/beta -> xnb bf16.
__global__ __launch_bounds__(512)
void k_projln(const float* __restrict__ A, const unsigned short* __restrict__ Bw,
              const float* __restrict__ bias, const float* __restrict__ gamma,
              const float* __restrict__ beta, unsigned short* __restrict__ xnb) {
    __shared__ unsigned short lsA[128 * 32];   // 8 KB
    __shared__ unsigned short lsB[512 * 32];   // 32 KB
    __shared__ float red[2][128][4];           // 4 KB (sum, sumsq) x row x wave-col

    const int t = threadIdx.x;
    const int tile_m = blockIdx.x * 128;
    const int w = t >> 6, l = t & 63, lr = l & 15, quad = l >> 4;
    const int wm = (w >> 2) * 64;      // wave row offset: 0 / 64
    const int wn = (w & 3) * 128;      // wave col offset: 0..384

    f32x4 acc[4][8];
#pragma unroll
    for (int i = 0; i < 4; i++)
#pragma unroll
        for (int j = 0; j < 8; j++) acc[i][j] = (f32x4){0.f, 0.f, 0.f, 0.f};

    // A staging: thread t covers row t>>2 (0..127), 8 fp32 at col (t&3)*8
    const int arow = t >> 2, acol = (t & 3) * 8;
    const float* baseA = A + (size_t)(tile_m + arow) * DBB + acol;
    unsigned short* ldsAdst = &lsA[arow * 32 + acol];

    // B staging: wave w covers output cols [w*64, w*64+64), 4 GLDS of 16 rows each
    const int srow = l >> 2, scol = (l & 3) * 8;
    const unsigned short* baseB = Bw + (size_t)(w * 64 + srow) * DBB + scol;
    unsigned short* ldsBw = &lsB[w * 64 * 32];

    // prefetch K-step 0 into regs
    float4 pa0 = *(const float4*)(baseA);
    float4 pa1 = *(const float4*)(baseA + 4);

    for (int kt = 0; kt < DBB / 32; ++kt) {
        __syncthreads();   // prior iter's frag reads done; also drains pa prefetch
        {
            unsigned short o[8] = {f2b(pa0.x), f2b(pa0.y), f2b(pa0.z), f2b(pa0.w),
                                   f2b(pa1.x), f2b(pa1.y), f2b(pa1.z), f2b(pa1.w)};
            *(uint4*)ldsAdst = *(const uint4*)o;
        }
        GLDS(baseB + kt * 32,            ldsBw);
        GLDS(baseB + kt * 32 + 16 * DBB, ldsBw + 16 * 32);
        GLDS(baseB + kt * 32 + 32 * DBB, ldsBw + 32 * 32);
        GLDS(baseB + kt * 32 + 48 * DBB, ldsBw + 48 * 32);
        __syncthreads();

        bf16x8 af[4];
#pragma unroll
        for (int i = 0; i < 4; i++)
            af[i] = *(const bf16x8*)(&lsA[(wm + i * 16 + lr) * 32 + quad * 8]);

        // issue next K-step's A loads; they fly under the MFMA phase and are
        // drained by the next top-of-loop barrier
        if (kt < DBB / 32 - 1) {
            pa0 = *(const float4*)(baseA + (kt + 1) * 32);
            pa1 = *(const float4*)(baseA + (kt + 1) * 32 + 4);
        }

#pragma unroll
        for (int j = 0; j < 8; j++) {
            const bf16x8 bfr = *(const bf16x8*)(&lsB[(wn + j * 16 + lr) * 32 + quad * 8]);
#pragma unroll
            for (int i = 0; i < 4; i++)
                acc[i][j] = __builtin_amdgcn_mfma_f32_16x16x32_bf16(af[i], bfr, acc[i][j], 0, 0, 0);
        }
    }

    // ---- bias (before LN stats, matching reference) ----
#pragma unroll
    for (int j = 0; j < 8; j++) {
        const float bv = bias[wn + j * 16 + lr];
#pragma unroll
        for (int i = 0; i < 4; i++)
#pragma unroll
            for (int r = 0; r < 4; r++) acc[i][j][r] += bv;
    }

    // ---- LN stats: per lane 16 rows x 8 cols; reduce cols, then 16 lr-lanes, then 4 waves ----
    float s[4][4], ss[4][4];
#pragma unroll
    for (int i = 0; i < 4; i++)
#pragma unroll
        for (int r = 0; r < 4; r++) {
            float a = 0.f, b = 0.f;
#pragma unroll
            for (int j = 0; j < 8; j++) { const float x = acc[i][j][r]; a += x; b += x * x; }
            s[i][r] = a; ss[i][r] = b;
        }
#pragma unroll
    for (int off = 1; off <= 8; off <<= 1) {
#pragma unroll
        for (int i = 0; i < 4; i++)
#pragma unroll
            for (int r = 0; r < 4; r++) {
                s[i][r]  += __shfl_xor(s[i][r], off);
                ss[i][r] += __shfl_xor(ss[i][r], off);
            }
    }
    if (lr == 0) {
#pragma unroll
        for (int i = 0; i < 4; i++)
#pragma unroll
            for (int r = 0; r < 4; r++) {
                const int rloc = wm + i * 16 + quad * 4 + r;
                red[0][rloc][w & 3] = s[i][r];
                red[1][rloc][w & 3] = ss[i][r];
            }
    }
    __syncthreads();

    float mu[4][4], rs[4][4];
#pragma unroll
    for (int i = 0; i < 4; i++)
#pragma unroll
        for (int r = 0; r < 4; r++) {
            const int rloc = wm + i * 16 + quad * 4 + r;
            const float S  = red[0][rloc][0] + red[0][rloc][1] + red[0][rloc][2] + red[0][rloc][3];
            const float SS = red[1][rloc][0] + red[1][rloc][1] + red[1][rloc][2] + red[1][rloc][3];
            const float m_ = S * (1.0f / 512.0f);
            const float v_ = SS * (1.0f / 512.0f) - m_ * m_;
            mu[i][r] = m_;
            rs[i][r] = rsqrtf(v_ + 1e-5f);
        }

    // ---- normalize + affine + store (camera c == fragment reg r, since rows%4==r) ----
#pragma unroll
    for (int j = 0; j < 8; j++) {
        const int col = wn + j * 16 + lr;
        float gv[4], bt[4];
#pragma unroll
        for (int r = 0; r < 4; r++) {
            gv[r] = gamma[r * D_H + col];
            bt[r] = beta[r * D_H + col];
        }
#pragma unroll
        for (int i = 0; i < 4; i++) {
            const int bidx = (tile_m + wm + i * 16 + quad * 4) >> 2;   // batch index
#pragma unroll
            for (int r = 0; r < 4; r++) {
                const float x = (acc[i][j][r] - mu[i][r]) * rs[i][r] * gv[r] + bt[r];
                xnb[((size_t)r * B_SZ + bidx) * D_H + col] = f2b(x);
            }
        }
    }
}

// ---------------- K3: per-camera fused gate/val GEMM + SiLU (m97 staging) ----------------
__global__ __launch_bounds__(256)
void k_swiglu(const unsigned short* __restrict__ xnb, const unsigned short* __restrict__ wg,
              const unsigned short* __restrict__ wv, unsigned short* __restrict__ hb) {
    __shared__ unsigned short lsA[128 * 32];
    __shared__ unsigned short lsG[128 * 32];
    __shared__ unsigned short lsV[128 * 32];
    const int t = threadIdx.x;
    const int tile_n = blockIdx.x * 128;
    const int tile_m = blockIdx.y * 128;
    const int cam = blockIdx.z;
    const unsigned short* Ac = xnb + (size_t)cam * B_SZ * D_H;
    const unsigned short* Gc = wg + (size_t)cam * D_H * D_H;
    const unsigned short* Vc = wv + (size_t)cam * D_H * D_H;
    const int w = t >> 6, l = t & 63, lr = l & 15, quad = l >> 4;
    const int wm = (w >> 1) * 64, wn = (w & 1) * 64;

    f32x4 ag[4][4], av[4][4];
#pragma unroll
    for (int i = 0; i < 4; i++)
#pragma unroll
        for (int j = 0; j < 4; j++) { ag[i][j] = (f32x4){0.f,0.f,0.f,0.f}; av[i][j] = (f32x4){0.f,0.f,0.f,0.f}; }

    const int srow = l >> 2, scol = (l & 3) * 8;
    const unsigned short* baseA = Ac + (size_t)(tile_m + w * 32 + srow) * D_H + scol;
    const unsigned short* baseG = Gc + (size_t)(tile_n + w * 32 + srow) * D_H + scol;
    const unsigned short* baseV = Vc + (size_t)(tile_n + w * 32 + srow) * D_H + scol;
    unsigned short* ldsAw = &lsA[w * 32 * 32];
    unsigned short* ldsGw = &lsG[w * 32 * 32];
    unsigned short* ldsVw = &lsV[w * 32 * 32];

    for (int kt = 0; kt < D_H / 32; ++kt) {
        __syncthreads();
        GLDS(baseA + kt * 32,            ldsAw);
        GLDS(baseA + kt * 32 + 16 * D_H, ldsAw + 16 * 32);
        GLDS(baseG + kt * 32,            ldsGw);
        GLDS(baseG + kt * 32 + 16 * D_H, ldsGw + 16 * 32);
        GLDS(baseV + kt * 32,            ldsVw);
        GLDS(baseV + kt * 32 + 16 * D_H, ldsVw + 16 * 32);
        __syncthreads();
        bf16x8 af[4];
#pragma unroll
        for (int i = 0; i < 4; i++)
            af[i] = *(const bf16x8*)(&lsA[(wm + i * 16 + lr) * 32 + quad * 8]);
#pragma unroll
        for (int j = 0; j < 4; j++) {
            bf16x8 gf = *(const bf16x8*)(&lsG[(wn + j * 16 + lr) * 32 + quad * 8]);
            bf16x8 vf = *(const bf16x8*)(&lsV[(wn + j * 16 + lr) * 32 + quad * 8]);
#pragma unroll
            for (int i = 0; i < 4; i++) {
                ag[i][j] = __builtin_amdgcn_mfma_f32_16x16x32_bf16(af[i], gf, ag[i][j], 0, 0, 0);
                av[i][j] = __builtin_amdgcn_mfma_f32_16x16x32_bf16(af[i], vf, av[i][j], 0, 0, 0);
            }
        }
    }
#pragma unroll
    for (int i = 0; i < 4; i++)
#pragma unroll
        for (int j = 0; j < 4; j++)
#pragma unroll
            for (int r = 0; r < 4; r++) {
                const int row = tile_m + wm + i * 16 + quad * 4 + r;
                const int col = tile_n + wn + j * 16 + lr;
                const float g = ag[i][j][r], v = av[i][j][r];
                const float h = g * v / (1.0f + __expf(-g));   // silu(g)*v
                hb[((size_t)cam * B_SZ + row) * D_H + col] = f2b(h);
            }
}

// ---------------- K4: per-camera out-proj (N padded 36->48, m97 staging) ----------------
__global__ __launch_bounds__(256)
void k_outproj(const unsigned short* __restrict__ hb, const unsigned short* __restrict__ wo,
               float* __restrict__ Abuf) {
    __shared__ unsigned short lsA[128 * 32];
    __shared__ unsigned short lsB[48 * 32];
    const int t = threadIdx.x;
    const int tile_m = blockIdx.y * 128;
    const int cam = blockIdx.z;
    const unsigned short* Ac = hb + (size_t)cam * B_SZ * D_H;
    const unsigned short* Bc = wo + (size_t)cam * 48 * D_H;
    const int w = t >> 6, l = t & 63, lr = l & 15, quad = l >> 4;
    const int srow = l >> 2, scol = (l & 3) * 8;

    f32x4 acc[2][3];
#pragma unroll
    for (int i = 0; i < 2; i++)
#pragma unroll
        for (int j = 0; j < 3; j++) acc[i][j] = (f32x4){0.f,0.f,0.f,0.f};

    const unsigned short* baseA = Ac + (size_t)(tile_m + w * 32 + srow) * D_H + scol;
    const unsigned short* baseB = Bc + (size_t)(w * 16 + srow) * D_H + scol;   // only valid w<3
    unsigned short* ldsAw = &lsA[w * 32 * 32];
    unsigned short* ldsBw = &lsB[w * 16 * 32];

    for (int kt = 0; kt < D_H / 32; ++kt) {
        __syncthreads();
        GLDS(baseA + kt * 32,            ldsAw);
        GLDS(baseA + kt * 32 + 16 * D_H, ldsAw + 16 * 32);
        if (w < 3) GLDS(baseB + kt * 32, ldsBw);
        __syncthreads();
        bf16x8 af[2], bfr[3];
#pragma unroll
        for (int i = 0; i < 2; i++)
            af[i] = *(const bf16x8*)(&lsA[(w * 32 + i * 16 + lr) * 32 + quad * 8]);
#pragma unroll
        for (int j = 0; j < 3; j++)
            bfr[j] = *(const bf16x8*)(&lsB[(j * 16 + lr) * 32 + quad * 8]);
#pragma unroll
        for (int i = 0; i < 2; i++)
#pragma unroll
            for (int j = 0; j < 3; j++)
                acc[i][j] = __builtin_amdgcn_mfma_f32_16x16x32_bf16(af[i], bfr[j], acc[i][j], 0, 0, 0);
    }
#pragma unroll
    for (int i = 0; i < 2; i++)
#pragma unroll
        for (int j = 0; j < 3; j++)
#pragma unroll
            for (int r = 0; r < 4; r++) {
                const int col = j * 16 + lr;
                if (col < 36) {
                    const int row = tile_m + w * 32 + i * 16 + quad * 4 + r;
                    Abuf[((size_t)cam * B_SZ + row) * 36 + col] = acc[i][j][r];
                }
            }
}

// ---------------- K5: skew, clip, expm (one thread per 6x6) ----------------
__global__ __launch_bounds__(128)
void k_expm(const float* __restrict__ Abuf, float* __restrict__ out) {
    const int gid = blockIdx.x * blockDim.x + threadIdx.x;
    if (gid >= B_SZ * C_CAM) return;
    const float* Ap = Abuf + (size_t)gid * 36;

    float a[36];
#pragma unroll
    for (int i = 0; i < 36; i++) a[i] = Ap[i];

    float S[36];
#pragma unroll
    for (int i = 0; i < 6; i++)
#pragma unroll
        for (int j = 0; j < 6; j++) S[i * 6 + j] = a[i * 6 + j] - a[j * 6 + i];

    float fr2 = 0.f;
#pragma unroll
    for (int i = 0; i < 36; i++) fr2 += S[i] * S[i];
    const float fr = sqrtf(fr2);
    const float sc = fminf(fr, 3.0f) / fmaxf(fr, 1e-8f) * 0.0625f;

    float As[36];
#pragma unroll
    for (int i = 0; i < 36; i++) As[i] = S[i] * sc;

    float E[36], T[36], tmp[36];
#pragma unroll
    for (int i = 0; i < 36; i++) { E[i] = (i % 7 == 0) ? 1.f : 0.f; T[i] = E[i]; }

#pragma unroll
    for (int k = 1; k <= 12; k++) {
        const float invk = 1.0f / (float)k;
#pragma unroll
        for (int i = 0; i < 6; i++)
#pragma unroll
            for (int j = 0; j < 6; j++) {
                float sum = 0.f;
#pragma unroll
                for (int q = 0; q < 6; q++) sum += T[i * 6 + q] * As[q * 6 + j];
                tmp[i * 6 + j] = sum * invk;
            }
#pragma unroll
        for (int i = 0; i < 36; i++) { T[i] = tmp[i]; E[i] += tmp[i]; }
    }
#pragma unroll
    for (int sq = 0; sq < 4; sq++) {
#pragma unroll
        for (int i = 0; i < 6; i++)
#pragma unroll
            for (int j = 0; j < 6; j++) {
                float sum = 0.f;
#pragma unroll
                for (int q = 0; q < 6; q++) sum += E[i * 6 + q] * E[q * 6 + j];
                tmp[i * 6 + j] = sum;
            }
#pragma unroll
        for (int i = 0; i < 36; i++) E[i] = tmp[i];
    }

    float* op = out + (size_t)gid * 36;
#pragma unroll
    for (int i = 0; i < 36; i++) op[i] = E[i];
}

// ---------------- launcher ----------------
extern "C" void kernel_launch(void* const* d_in, const int* in_sizes, int n_in,
                              void* d_out, int out_size, void* d_ws, size_t ws_size,
                              hipStream_t stream) {
    const float* thumb  = (const float*)d_in[0];
    const float* proj_w = (const float*)d_in[1];
    const float* proj_b = (const float*)d_in[2];
    const float* gamma  = (const float*)d_in[3];
    const float* beta   = (const float*)d_in[4];
    const float* w_gate = (const float*)d_in[5];
    const float* w_val  = (const float*)d_in[6];
    const float* w_out  = (const float*)d_in[7];

    char* ws = (char*)d_ws;
    // layout (~141 MB total):
    //   xnb  : [0, 64 MiB)            bf16 [C][B][512]  (dead after k_swiglu)
    //   Abuf : [0, 9 MiB)             fp32 [C][B][36]   (overlaps xnb; written after xnb dead)
    //   hb   : [64 MiB, 128 MiB)      bf16 [C][B][512]
    //   weights: pwb/wgb/wvb/wob past 128 MiB
    unsigned short* xnb  = (unsigned short*)(ws);
    float*          Abuf = (float*)(ws);
    unsigned short* hb   = (unsigned short*)(ws + 67108864);
    unsigned short* pwb  = (unsigned short*)(ws + 134217728);
    unsigned short* wgb  = (unsigned short*)(ws + 136314880);
    unsigned short* wvb  = (unsigned short*)(ws + 138412032);
    unsigned short* wob  = (unsigned short*)(ws + 140509184);

    hipLaunchKernelGGL(k_cvt, dim3(1024), dim3(256), 0, stream, proj_w, pwb, D_H * DBB);
    hipLaunchKernelGGL(k_cvt, dim3(1024), dim3(256), 0, stream, w_gate, wgb, C_CAM * D_H * D_H);
    hipLaunchKernelGGL(k_cvt, dim3(1024), dim3(256), 0, stream, w_val, wvb, C_CAM * D_H * D_H);
    hipLaunchKernelGGL(k_cvt_wout, dim3((C_CAM * 48 * D_H + 255) / 256), dim3(256), 0, stream, w_out, wob);

    hipLaunchKernelGGL(k_projln, dim3(B_SZ * C_CAM / 128), dim3(512), 0, stream,
                       thumb, pwb, proj_b, gamma, beta, xnb);
    hipLaunchKernelGGL(k_swiglu, dim3(4, 128, 4), dim3(256), 0, stream, xnb, wgb, wvb, hb);
    hipLaunchKernelGGL(k_outproj, dim3(1, 128, 4), dim3(256), 0, stream, hb, wob, Abuf);
    hipLaunchKernelGGL(k_expm, dim3(B_SZ * C_CAM / 128), dim3(128), 0, stream, Abuf, (float*)d_out);
}

// Round 5
// 1058.332 us; speedup vs baseline: 1.1177x; 1.0209x over previous
//
#include <hip/hip_runtime.h>
#include <cstdint>
#include <cstddef>

// DeltaMPredictor: proj(2048->512) + per-cam LN + per-cam SwiGLU + proj->36
// + skew/clip/expm(6x6).
//
// R5 = R4 resubmitted (bench infra failed twice; kernel audited sound —
// see R1/R2 precedent where identical source later passed).
//  K0 k_cvt_all : one launch converts proj_w/w_gate/w_val (bf16) + w_out
//                 (bf16, padded 36->48, XOR-swizzled rows for conflict-free
//                 LDS frag reads later).
//  K1 k_projln  : fused proj GEMM (fp32 A read once) + bias + LayerNorm
//                 (unchanged from R3, verified at 1080 us run).
//  K2 k_swiglu_out : fused per-camera SwiGLU + out-proj. 64x512 h panel per
//                 512-thread block; h kept in LDS (XOR-swizzled), out-GEMM
//                 done in-block by waves 0-3. Eliminates the hb global
//                 round-trip (128 MB) and the separate k_outproj kernel.
//  K3 k_expm    : unchanged.

#define B_SZ   16384
#define C_CAM  4
#define DBB    2048
#define D_H    512

typedef __attribute__((ext_vector_type(8))) short  bf16x8;
typedef __attribute__((ext_vector_type(4))) float  f32x4;

__device__ __forceinline__ unsigned short f2b(float f) {
    union { float f; unsigned u; } v; v.f = f;
    unsigned r = (v.u + 0x7FFFu + ((v.u >> 16) & 1u)) >> 16;   // RNE
    return (unsigned short)r;
}

// async global->LDS, 16B per lane, dest = wave-uniform base + lane*16
#define GLDS(g, l) __builtin_amdgcn_global_load_lds( \
    (const __attribute__((address_space(1))) unsigned int*)(g), \
    (__attribute__((address_space(3))) unsigned int*)(l), 16, 0, 0)

// ---------------- K0: all weight conversions in one launch ----------------
// ranges: [0,1Mi) proj_w -> pwb ; [1Mi,2Mi) w_gate -> wgb ; [2Mi,3Mi) w_val
// -> wvb ; [3Mi, 3Mi+96Ki) w_out -> wob (padded to [C][48][512], rows 36..47
// zero, element col swizzled: col ^ ((row&7)<<3) so a GLDS-linear LDS copy
// reads conflict-free as MFMA B-frags).
__global__ __launch_bounds__(256)
void k_cvt_all(const float* __restrict__ proj_w, const float* __restrict__ w_gate,
               const float* __restrict__ w_val, const float* __restrict__ w_out,
               unsigned short* __restrict__ pwb, unsigned short* __restrict__ wgb,
               unsigned short* __restrict__ wvb, unsigned short* __restrict__ wob) {
    const int idx = blockIdx.x * blockDim.x + threadIdx.x;
    const int N1 = D_H * DBB;             // 1048576
    const int N2 = C_CAM * D_H * D_H;     // 1048576
    if (idx < N1) {
        pwb[idx] = f2b(proj_w[idx]);
    } else if (idx < N1 + N2) {
        const int i = idx - N1;
        wgb[i] = f2b(w_gate[i]);
    } else if (idx < N1 + 2 * N2) {
        const int i = idx - N1 - N2;
        wvb[i] = f2b(w_val[i]);
    } else if (idx < N1 + 2 * N2 + C_CAM * 48 * D_H) {
        const int i = idx - N1 - 2 * N2;
        const int c = i / (48 * D_H);
        const int rem = i - c * 48 * D_H;
        const int row = rem >> 9;
        const int col = rem & (D_H - 1);
        const int dcol = col ^ ((row & 7) << 3);          // 16B-block swizzle
        wob[c * 48 * D_H + row * D_H + dcol] =
            (row < 36) ? f2b(w_out[((size_t)c * 36 + row) * D_H + col]) : (unsigned short)0;
    }
}

// ---------------- K1 fused: proj GEMM (fp32 A, read once) + bias + LayerNorm ----------------
// (unchanged from the verified R3 kernel)
__global__ __launch_bounds__(512)
void k_projln(const float* __restrict__ A, const unsigned short* __restrict__ Bw,
              const float* __restrict__ bias, const float* __restrict__ gamma,
              const float* __restrict__ beta, unsigned short* __restrict__ xnb) {
    __shared__ unsigned short lsA[128 * 32];   // 8 KB
    __shared__ unsigned short lsB[512 * 32];   // 32 KB
    __shared__ float red[2][128][4];           // 4 KB (sum, sumsq) x row x wave-col

    const int t = threadIdx.x;
    const int tile_m = blockIdx.x * 128;
    const int w = t >> 6, l = t & 63, lr = l & 15, quad = l >> 4;
    const int wm = (w >> 2) * 64;      // wave row offset: 0 / 64
    const int wn = (w & 3) * 128;      // wave col offset: 0..384

    f32x4 acc[4][8];
#pragma unroll
    for (int i = 0; i < 4; i++)
#pragma unroll
        for (int j = 0; j < 8; j++) acc[i][j] = (f32x4){0.f, 0.f, 0.f, 0.f};

    const int arow = t >> 2, acol = (t & 3) * 8;
    const float* baseA = A + (size_t)(tile_m + arow) * DBB + acol;
    unsigned short* ldsAdst = &lsA[arow * 32 + acol];

    const int srow = l >> 2, scol = (l & 3) * 8;
    const unsigned short* baseB = Bw + (size_t)(w * 64 + srow) * DBB + scol;
    unsigned short* ldsBw = &lsB[w * 64 * 32];

    float4 pa0 = *(const float4*)(baseA);
    float4 pa1 = *(const float4*)(baseA + 4);

    for (int kt = 0; kt < DBB / 32; ++kt) {
        __syncthreads();
        {
            unsigned short o[8] = {f2b(pa0.x), f2b(pa0.y), f2b(pa0.z), f2b(pa0.w),
                                   f2b(pa1.x), f2b(pa1.y), f2b(pa1.z), f2b(pa1.w)};
            *(uint4*)ldsAdst = *(const uint4*)o;
        }
        GLDS(baseB + kt * 32,            ldsBw);
        GLDS(baseB + kt * 32 + 16 * DBB, ldsBw + 16 * 32);
        GLDS(baseB + kt * 32 + 32 * DBB, ldsBw + 32 * 32);
        GLDS(baseB + kt * 32 + 48 * DBB, ldsBw + 48 * 32);
        __syncthreads();

        bf16x8 af[4];
#pragma unroll
        for (int i = 0; i < 4; i++)
            af[i] = *(const bf16x8*)(&lsA[(wm + i * 16 + lr) * 32 + quad * 8]);

        if (kt < DBB / 32 - 1) {
            pa0 = *(const float4*)(baseA + (kt + 1) * 32);
            pa1 = *(const float4*)(baseA + (kt + 1) * 32 + 4);
        }

#pragma unroll
        for (int j = 0; j < 8; j++) {
            const bf16x8 bfr = *(const bf16x8*)(&lsB[(wn + j * 16 + lr) * 32 + quad * 8]);
#pragma unroll
            for (int i = 0; i < 4; i++)
                acc[i][j] = __builtin_amdgcn_mfma_f32_16x16x32_bf16(af[i], bfr, acc[i][j], 0, 0, 0);
        }
    }

#pragma unroll
    for (int j = 0; j < 8; j++) {
        const float bv = bias[wn + j * 16 + lr];
#pragma unroll
        for (int i = 0; i < 4; i++)
#pragma unroll
            for (int r = 0; r < 4; r++) acc[i][j][r] += bv;
    }

    float s[4][4], ss[4][4];
#pragma unroll
    for (int i = 0; i < 4; i++)
#pragma unroll
        for (int r = 0; r < 4; r++) {
            float a = 0.f, b = 0.f;
#pragma unroll
            for (int j = 0; j < 8; j++) { const float x = acc[i][j][r]; a += x; b += x * x; }
            s[i][r] = a; ss[i][r] = b;
        }
#pragma unroll
    for (int off = 1; off <= 8; off <<= 1) {
#pragma unroll
        for (int i = 0; i < 4; i++)
#pragma unroll
            for (int r = 0; r < 4; r++) {
                s[i][r]  += __shfl_xor(s[i][r], off);
                ss[i][r] += __shfl_xor(ss[i][r], off);
            }
    }
    if (lr == 0) {
#pragma unroll
        for (int i = 0; i < 4; i++)
#pragma unroll
            for (int r = 0; r < 4; r++) {
                const int rloc = wm + i * 16 + quad * 4 + r;
                red[0][rloc][w & 3] = s[i][r];
                red[1][rloc][w & 3] = ss[i][r];
            }
    }
    __syncthreads();

    float mu[4][4], rs[4][4];
#pragma unroll
    for (int i = 0; i < 4; i++)
#pragma unroll
        for (int r = 0; r < 4; r++) {
            const int rloc = wm + i * 16 + quad * 4 + r;
            const float S  = red[0][rloc][0] + red[0][rloc][1] + red[0][rloc][2] + red[0][rloc][3];
            const float SS = red[1][rloc][0] + red[1][rloc][1] + red[1][rloc][2] + red[1][rloc][3];
            const float m_ = S * (1.0f / 512.0f);
            const float v_ = SS * (1.0f / 512.0f) - m_ * m_;
            mu[i][r] = m_;
            rs[i][r] = rsqrtf(v_ + 1e-5f);
        }

#pragma unroll
    for (int j = 0; j < 8; j++) {
        const int col = wn + j * 16 + lr;
        float gv[4], bt[4];
#pragma unroll
        for (int r = 0; r < 4; r++) {
            gv[r] = gamma[r * D_H + col];
            bt[r] = beta[r * D_H + col];
        }
#pragma unroll
        for (int i = 0; i < 4; i++) {
            const int bidx = (tile_m + wm + i * 16 + quad * 4) >> 2;
#pragma unroll
            for (int r = 0; r < 4; r++) {
                const float x = (acc[i][j][r] - mu[i][r]) * rs[i][r] * gv[r] + bt[r];
                xnb[((size_t)r * B_SZ + bidx) * D_H + col] = f2b(x);
            }
        }
    }
}

// ---------------- K2 fused: per-camera SwiGLU + out-proj ----------------
// Block = 512 threads (8 waves). Rows [tile_m, tile_m+64) of one camera,
// all 512 h-cols. Wave w computes the 64x64 patch cols [w*64,(w+1)*64) for
// BOTH gate and val (acc 2x16 f32x4 = 128 VGPR). After the K-loop:
// h = silu(g)*v -> bf16 -> LDS (XOR-swizzled [64][512], overlaying the G/V
// staging buffers), w_out staged (pre-swizzled by k_cvt_all), then waves 0-3
// each compute one 16-row m-frag of out[64][48] over full K=512.
__global__ __launch_bounds__(512)
void k_swiglu_out(const unsigned short* __restrict__ xnb, const unsigned short* __restrict__ wg,
                  const unsigned short* __restrict__ wv, const unsigned short* __restrict__ wo,
                  float* __restrict__ Abuf) {
    __shared__ unsigned short lsA[64 * 32];        // 4 KB
    __shared__ unsigned short lsGV[2][512 * 32];   // 64 KB; becomes hls after main loop
    __shared__ unsigned short lsO[48 * 512];       // 48 KB (w_out, pre-swizzled)

    const int t = threadIdx.x;
    const int tile_m = blockIdx.x * 64;
    const int cam = blockIdx.y;
    const unsigned short* Ac = xnb + ((size_t)cam * B_SZ + tile_m) * D_H;
    const unsigned short* Gc = wg + (size_t)cam * D_H * D_H;
    const unsigned short* Vc = wv + (size_t)cam * D_H * D_H;
    const unsigned short* Oc = wo + (size_t)cam * 48 * D_H;
    const int w = t >> 6, l = t & 63, lr = l & 15, quad = l >> 4;
    const int wn = w * 64;                         // this wave's h-col range

    f32x4 ag[4][4], av[4][4];
#pragma unroll
    for (int i = 0; i < 4; i++)
#pragma unroll
        for (int j = 0; j < 4; j++) { ag[i][j] = (f32x4){0.f,0.f,0.f,0.f}; av[i][j] = (f32x4){0.f,0.f,0.f,0.f}; }

    const int srow = l >> 2, scol = (l & 3) * 8;
    // A staging: waves 0-3 stage 16 rows each (64 rows total)
    const unsigned short* baseA = Ac + (size_t)((w & 3) * 16 + srow) * D_H + scol;
    unsigned short* ldsAw = &lsA[(w & 3) * 16 * 32];
    // G/V staging: wave w stages weight rows [wn, wn+64)
    const unsigned short* baseG = Gc + (size_t)(wn + srow) * D_H + scol;
    const unsigned short* baseV = Vc + (size_t)(wn + srow) * D_H + scol;
    unsigned short* ldsGw = &lsGV[0][wn * 32];
    unsigned short* ldsVw = &lsGV[1][wn * 32];

    for (int kt = 0; kt < D_H / 32; ++kt) {
        __syncthreads();
        if (w < 4) GLDS(baseA + kt * 32, ldsAw);
        GLDS(baseG + kt * 32,            ldsGw);
        GLDS(baseG + kt * 32 + 16 * D_H, ldsGw + 16 * 32);
        GLDS(baseG + kt * 32 + 32 * D_H, ldsGw + 32 * 32);
        GLDS(baseG + kt * 32 + 48 * D_H, ldsGw + 48 * 32);
        GLDS(baseV + kt * 32,            ldsVw);
        GLDS(baseV + kt * 32 + 16 * D_H, ldsVw + 16 * 32);
        GLDS(baseV + kt * 32 + 32 * D_H, ldsVw + 32 * 32);
        GLDS(baseV + kt * 32 + 48 * D_H, ldsVw + 48 * 32);
        __syncthreads();
        bf16x8 af[4];
#pragma unroll
        for (int i = 0; i < 4; i++)
            af[i] = *(const bf16x8*)(&lsA[(i * 16 + lr) * 32 + quad * 8]);
#pragma unroll
        for (int j = 0; j < 4; j++) {
            const bf16x8 gf = *(const bf16x8*)(&lsGV[0][(wn + j * 16 + lr) * 32 + quad * 8]);
            const bf16x8 vf = *(const bf16x8*)(&lsGV[1][(wn + j * 16 + lr) * 32 + quad * 8]);
#pragma unroll
            for (int i = 0; i < 4; i++) {
                ag[i][j] = __builtin_amdgcn_mfma_f32_16x16x32_bf16(af[i], gf, ag[i][j], 0, 0, 0);
                av[i][j] = __builtin_amdgcn_mfma_f32_16x16x32_bf16(af[i], vf, av[i][j], 0, 0, 0);
            }
        }
    }

    // h = silu(g)*v in regs
    unsigned short hreg[4][4][4];
#pragma unroll
    for (int i = 0; i < 4; i++)
#pragma unroll
        for (int j = 0; j < 4; j++)
#pragma unroll
            for (int r = 0; r < 4; r++) {
                const float g = ag[i][j][r], v = av[i][j][r];
                hreg[i][j][r] = f2b(g * v / (1.0f + __expf(-g)));
            }

    __syncthreads();   // all G/V frag reads done -> safe to overlay hls

    // stage w_out [48][512] (pre-swizzled in global) linearly: 48 KB = 48 instrs
#pragma unroll
    for (int p = 0; p < 6; p++) {
        const int inst = w * 6 + p;
        GLDS(Oc + inst * 512 + l * 8, &lsO[inst * 512]);
    }

    // write h -> hls (overlay lsGV), XOR-swizzled: elem col ^ ((row&7)<<3)
    unsigned short* hls = &lsGV[0][0];
#pragma unroll
    for (int i = 0; i < 4; i++)
#pragma unroll
        for (int r = 0; r < 4; r++) {
            const int row = i * 16 + quad * 4 + r;
            const int sw = (row & 7) << 3;
#pragma unroll
            for (int j = 0; j < 4; j++) {
                const int col = wn + j * 16 + lr;
                hls[row * D_H + (col ^ sw)] = hreg[i][j][r];
            }
        }

    __syncthreads();   // hls writes + w_out GLDS drained

    // out-GEMM: waves 0-3, wave w -> m-frag rows [w*16, w*16+16), 48 cols, K=512
    if (w < 4) {
        f32x4 o[3];
#pragma unroll
        for (int j = 0; j < 3; j++) o[j] = (f32x4){0.f,0.f,0.f,0.f};
        const int arow = w * 16 + lr;
        const int asw = (arow & 7) << 3;
#pragma unroll
        for (int ks = 0; ks < D_H / 32; ++ks) {
            const bf16x8 af = *(const bf16x8*)(&hls[arow * D_H + ((ks * 32 + quad * 8) ^ asw)]);
#pragma unroll
            for (int j = 0; j < 3; j++) {
                const int brow = j * 16 + lr;
                const bf16x8 bfr = *(const bf16x8*)(&lsO[brow * D_H + ((ks * 32 + quad * 8) ^ ((brow & 7) << 3))]);
                o[j] = __builtin_amdgcn_mfma_f32_16x16x32_bf16(af, bfr, o[j], 0, 0, 0);
            }
        }
#pragma unroll
        for (int j = 0; j < 3; j++)
#pragma unroll
            for (int r = 0; r < 4; r++) {
                const int col = j * 16 + lr;
                if (col < 36) {
                    const int row = tile_m + w * 16 + quad * 4 + r;
                    Abuf[((size_t)cam * B_SZ + row) * 36 + col] = o[j][r];
                }
            }
    }
}

// ---------------- K3: skew, clip, expm (one thread per 6x6) ----------------
__global__ __launch_bounds__(128)
void k_expm(const float* __restrict__ Abuf, float* __restrict__ out) {
    const int gid = blockIdx.x * blockDim.x + threadIdx.x;
    if (gid >= B_SZ * C_CAM) return;
    const float* Ap = Abuf + (size_t)gid * 36;

    float a[36];
#pragma unroll
    for (int i = 0; i < 36; i++) a[i] = Ap[i];

    float S[36];
#pragma unroll
    for (int i = 0; i < 6; i++)
#pragma unroll
        for (int j = 0; j < 6; j++) S[i * 6 + j] = a[i * 6 + j] - a[j * 6 + i];

    float fr2 = 0.f;
#pragma unroll
    for (int i = 0; i < 36; i++) fr2 += S[i] * S[i];
    const float fr = sqrtf(fr2);
    const float sc = fminf(fr, 3.0f) / fmaxf(fr, 1e-8f) * 0.0625f;

    float As[36];
#pragma unroll
    for (int i = 0; i < 36; i++) As[i] = S[i] * sc;

    float E[36], T[36], tmp[36];
#pragma unroll
    for (int i = 0; i < 36; i++) { E[i] = (i % 7 == 0) ? 1.f : 0.f; T[i] = E[i]; }

#pragma unroll
    for (int k = 1; k <= 12; k++) {
        const float invk = 1.0f / (float)k;
#pragma unroll
        for (int i = 0; i < 6; i++)
#pragma unroll
            for (int j = 0; j < 6; j++) {
                float sum = 0.f;
#pragma unroll
                for (int q = 0; q < 6; q++) sum += T[i * 6 + q] * As[q * 6 + j];
                tmp[i * 6 + j] = sum * invk;
            }
#pragma unroll
        for (int i = 0; i < 36; i++) { T[i] = tmp[i]; E[i] += tmp[i]; }
    }
#pragma unroll
    for (int sq = 0; sq < 4; sq++) {
#pragma unroll
        for (int i = 0; i < 6; i++)
#pragma unroll
            for (int j = 0; j < 6; j++) {
                float sum = 0.f;
#pragma unroll
                for (int q = 0; q < 6; q++) sum += E[i * 6 + q] * E[q * 6 + j];
                tmp[i * 6 + j] = sum;
            }
#pragma unroll
        for (int i = 0; i < 36; i++) E[i] = tmp[i];
    }

    float* op = out + (size_t)gid * 36;
#pragma unroll
    for (int i = 0; i < 36; i++) op[i] = E[i];
}

// ---------------- launcher ----------------
extern "C" void kernel_launch(void* const* d_in, const int* in_sizes, int n_in,
                              void* d_out, int out_size, void* d_ws, size_t ws_size,
                              hipStream_t stream) {
    const float* thumb  = (const float*)d_in[0];
    const float* proj_w = (const float*)d_in[1];
    const float* proj_b = (const float*)d_in[2];
    const float* gamma  = (const float*)d_in[3];
    const float* beta   = (const float*)d_in[4];
    const float* w_gate = (const float*)d_in[5];
    const float* w_val  = (const float*)d_in[6];
    const float* w_out  = (const float*)d_in[7];

    char* ws = (char*)d_ws;
    // layout (~141 MB total):
    //   xnb  : [0, 64 MiB)        bf16 [C][B][512]
    //   Abuf : [64 MiB, +9 MiB)   fp32 [C][B][36]   (disjoint from xnb: both
    //                             live inside k_swiglu_out)
    //   weights at 128 MiB: pwb 2 MiB, wgb 2 MiB, wvb 2 MiB, wob 192 KiB
    unsigned short* xnb  = (unsigned short*)(ws);
    float*          Abuf = (float*)(ws + 67108864);
    unsigned short* pwb  = (unsigned short*)(ws + 134217728);
    unsigned short* wgb  = (unsigned short*)(ws + 136314880);
    unsigned short* wvb  = (unsigned short*)(ws + 138412032);
    unsigned short* wob  = (unsigned short*)(ws + 140509184);

    const int cvt_total = D_H * DBB + 2 * C_CAM * D_H * D_H + C_CAM * 48 * D_H;
    hipLaunchKernelGGL(k_cvt_all, dim3((cvt_total + 255) / 256), dim3(256), 0, stream,
                       proj_w, w_gate, w_val, w_out, pwb, wgb, wvb, wob);

    hipLaunchKernelGGL(k_projln, dim3(B_SZ * C_CAM / 128), dim3(512), 0, stream,
                       thumb, pwb, proj_b, gamma, beta, xnb);
    hipLaunchKernelGGL(k_swiglu_out, dim3(B_SZ / 64, C_CAM), dim3(512), 0, stream,
                       xnb, wgb, wvb, wob, Abuf);
    hipLaunchKernelGGL(k_expm, dim3(B_SZ * C_CAM / 128), dim3(128), 0, stream, Abuf, (float*)d_out);
}